// Round 1
// baseline (2300.681 us; speedup 1.0000x reference)
//
#include <hip/hip_runtime.h>
#include <hip/hip_bf16.h>

// APPNP: z = MLP(x); then 10x: x_{k+1} = 0.9 * A_hat x_k + 0.1 * z
// A_hat = D^-1/2 (A + I) D^-1/2, degree at target (col) nodes.

#define HIDDEN 256
#define OUTF   64
#define ALPHA_F 0.1f

// ---------- int64/int32 edge-index hedge ----------
// Reference creates int64 edge_index with values < 2^31. If the harness kept
// int64 storage, every odd int32 word (high half) is 0. If it converted to
// int32, odd words are random node ids (P(all 16 zero) ~ 1e-80).
__device__ inline bool detect_i64(const int* __restrict__ p) {
    int acc = 0;
#pragma unroll
    for (int i = 0; i < 16; ++i) acc |= p[2 * i + 1];
    return acc == 0;
}

__device__ inline int load_idx(const void* eiv, long long flat, bool is64) {
    if (is64) return (int)((const long long*)eiv)[flat];
    return ((const int*)eiv)[flat];
}

// ---------- degree count ----------
__global__ __launch_bounds__(512) void count_deg_kernel(const void* __restrict__ eiv,
                                                        long long E, int* __restrict__ deg,
                                                        int n) {
    bool is64 = detect_i64((const int*)eiv);
    long long e = (long long)blockIdx.x * blockDim.x + threadIdx.x;
    if (e >= E) return;
    int c = load_idx(eiv, E + e, is64);
    if ((unsigned)c < (unsigned)n) atomicAdd(&deg[c], 1);
}

// ---------- dinv = rsqrt(deg + 1) (self-loop included) ----------
__global__ __launch_bounds__(256) void dinv_kernel(const int* __restrict__ deg,
                                                   float* __restrict__ dinv, int n) {
    int i = blockIdx.x * 256 + threadIdx.x;
    if (i < n) dinv[i] = rsqrtf((float)(deg[i] + 1));
}

// ---------- single-block exclusive scan over deg -> ofs[0..n] ----------
__global__ __launch_bounds__(1024) void scan_kernel(const int* __restrict__ deg,
                                                    int* __restrict__ ofs, int n) {
    __shared__ int s[1024];
    __shared__ int carry_s;
    int t = threadIdx.x;
    if (t == 0) carry_s = 0;
    __syncthreads();
    for (int base = 0; base < n; base += 1024) {
        int i = base + t;
        int v = (i < n) ? deg[i] : 0;
        s[t] = v;
        __syncthreads();
        for (int o = 1; o < 1024; o <<= 1) {
            int tv = (t >= o) ? s[t - o] : 0;
            __syncthreads();
            s[t] += tv;
            __syncthreads();
        }
        int carry = carry_s;
        if (i < n) ofs[i] = carry + s[t] - v;  // exclusive
        __syncthreads();
        if (t == 0) carry_s += s[1023];
        __syncthreads();
    }
    if (t == 0) ofs[n] = carry_s;
}

__global__ __launch_bounds__(256) void copy_cursor_kernel(const int* __restrict__ ofs,
                                                          int* __restrict__ cur, int n) {
    int i = blockIdx.x * 256 + threadIdx.x;
    if (i < n) cur[i] = ofs[i];
}

// ---------- CSR fill (by target node) ----------
__global__ __launch_bounds__(512) void fill_csr_kernel(const void* __restrict__ eiv,
                                                       long long E, int* __restrict__ cur,
                                                       int* __restrict__ csr_src, int n) {
    bool is64 = detect_i64((const int*)eiv);
    long long e = (long long)blockIdx.x * blockDim.x + threadIdx.x;
    if (e >= E) return;
    int r = load_idx(eiv, e, is64);
    int c = load_idx(eiv, E + e, is64);
    if ((unsigned)c >= (unsigned)n || (unsigned)r >= (unsigned)n) return;
    int pos = atomicAdd(&cur[c], 1);
    csr_src[pos] = r;
}

// ---------- fused MLP: z = relu(x@w1.T + b1) @ w2.T + b2 ----------
// Block: 256 threads, 64 nodes. fp32, LDS-staged tiles.
#define MLP_BM 64
__global__ __launch_bounds__(256) void mlp_kernel(const float* __restrict__ x,
                                                  const float* __restrict__ w1,
                                                  const float* __restrict__ b1,
                                                  const float* __restrict__ w2,
                                                  const float* __restrict__ b2,
                                                  float* __restrict__ z, int n) {
    __shared__ float xs[MLP_BM][33];   // [m][k2] chunk of x
    __shared__ float w1s[32][72];      // [k2][f_local] transposed w1 tile (row=288B, 16B aligned)
    __shared__ float hs[MLP_BM][65];   // [m][f_local] relu'd hidden
    __shared__ float w2s[64][72];      // [j][f_local]

    int t = threadIdx.x;
    int mg = t & 31;        // node sub-index (m and m+32)
    int fg = t >> 5;        // feature group 0..7
    int node0 = blockIdx.x * MLP_BM;

    float zacc[2][8];
#pragma unroll
    for (int a = 0; a < 2; ++a)
#pragma unroll
        for (int b = 0; b < 8; ++b) zacc[a][b] = 0.f;

    for (int fb = 0; fb < 4; ++fb) {
        int f0 = fb * 64;
        float hacc[2][8];
#pragma unroll
        for (int a = 0; a < 2; ++a)
#pragma unroll
            for (int b = 0; b < 8; ++b) hacc[a][b] = 0.f;

        for (int kb = 0; kb < 8; ++kb) {
            int k0 = kb * 32;
            // stage xs: 64 nodes x 32 k
#pragma unroll
            for (int i = 0; i < 8; ++i) {
                int q = i * 256 + t;
                int m = q >> 5, k = q & 31;
                int node = node0 + m;
                xs[m][k] = (node < n) ? x[(size_t)node * HIDDEN + k0 + k] : 0.f;
            }
            // stage w1s transposed: 64 f x 32 k
#pragma unroll
            for (int i = 0; i < 8; ++i) {
                int q = i * 256 + t;
                int f = q >> 5, k = q & 31;
                w1s[k][f] = w1[(size_t)(f0 + f) * HIDDEN + k0 + k];
            }
            __syncthreads();
#pragma unroll 8
            for (int k2 = 0; k2 < 32; ++k2) {
                float xa = xs[mg][k2];
                float xb = xs[mg + 32][k2];
                const float4 wlo = *(const float4*)&w1s[k2][fg * 8];
                const float4 whi = *(const float4*)&w1s[k2][fg * 8 + 4];
                hacc[0][0] = fmaf(xa, wlo.x, hacc[0][0]);
                hacc[0][1] = fmaf(xa, wlo.y, hacc[0][1]);
                hacc[0][2] = fmaf(xa, wlo.z, hacc[0][2]);
                hacc[0][3] = fmaf(xa, wlo.w, hacc[0][3]);
                hacc[0][4] = fmaf(xa, whi.x, hacc[0][4]);
                hacc[0][5] = fmaf(xa, whi.y, hacc[0][5]);
                hacc[0][6] = fmaf(xa, whi.z, hacc[0][6]);
                hacc[0][7] = fmaf(xa, whi.w, hacc[0][7]);
                hacc[1][0] = fmaf(xb, wlo.x, hacc[1][0]);
                hacc[1][1] = fmaf(xb, wlo.y, hacc[1][1]);
                hacc[1][2] = fmaf(xb, wlo.z, hacc[1][2]);
                hacc[1][3] = fmaf(xb, wlo.w, hacc[1][3]);
                hacc[1][4] = fmaf(xb, whi.x, hacc[1][4]);
                hacc[1][5] = fmaf(xb, whi.y, hacc[1][5]);
                hacc[1][6] = fmaf(xb, whi.z, hacc[1][6]);
                hacc[1][7] = fmaf(xb, whi.w, hacc[1][7]);
            }
            __syncthreads();
        }
        // bias + relu -> hs
#pragma unroll
        for (int ff = 0; ff < 8; ++ff) {
            int f = fg * 8 + ff;
            float bb = b1[f0 + f];
            hs[mg][f] = fmaxf(hacc[0][ff] + bb, 0.f);
            hs[mg + 32][f] = fmaxf(hacc[1][ff] + bb, 0.f);
        }
        // stage w2s: 64 j x 64 f (float4)
#pragma unroll
        for (int i = 0; i < 4; ++i) {
            int q = i * 256 + t;  // 1024 float4 slots
            int j = q >> 4, f4 = q & 15;
            *(float4*)&w2s[j][f4 * 4] = *(const float4*)&w2[(size_t)j * HIDDEN + f0 + f4 * 4];
        }
        __syncthreads();
        // z-phase
#pragma unroll 4
        for (int f2 = 0; f2 < 64; ++f2) {
            float ha = hs[mg][f2];
            float hb = hs[mg + 32][f2];
#pragma unroll
            for (int jj = 0; jj < 8; ++jj) {
                float wv = w2s[fg * 8 + jj][f2];
                zacc[0][jj] = fmaf(ha, wv, zacc[0][jj]);
                zacc[1][jj] = fmaf(hb, wv, zacc[1][jj]);
            }
        }
        __syncthreads();
    }
    // transpose z through hs for coalesced store
#pragma unroll
    for (int jj = 0; jj < 8; ++jj) {
        hs[mg][fg * 8 + jj] = zacc[0][jj];
        hs[mg + 32][fg * 8 + jj] = zacc[1][jj];
    }
    __syncthreads();
#pragma unroll
    for (int i = 0; i < 16; ++i) {
        int q = i * 256 + t;
        int m = q >> 6, j = q & 63;
        int node = node0 + m;
        if (node < n) z[(size_t)node * OUTF + j] = hs[m][j] + b2[j];
    }
}

// ---------- propagation step: xn = 0.9 * A_hat xk + 0.1 * x0 ----------
// 16 threads per node, float4 per thread (64 feats).
__global__ __launch_bounds__(256) void prop_kernel(const float* __restrict__ xk,
                                                   const float* __restrict__ x0,
                                                   float* __restrict__ xn,
                                                   const int* __restrict__ ofs,
                                                   const int* __restrict__ csr_src,
                                                   const float* __restrict__ dinv, int n) {
    int g = blockIdx.x * 256 + threadIdx.x;
    int node = g >> 4;
    int part = g & 15;
    if (node >= n) return;

    const float4* xk4 = (const float4*)xk;
    int beg = ofs[node];
    int end = ofs[node + 1];
    float di = dinv[node];

    float4 acc = make_float4(0.f, 0.f, 0.f, 0.f);
    for (int e = beg; e < end; ++e) {
        int s = csr_src[e];
        float w = di * dinv[s];
        float4 v = xk4[(size_t)s * 16 + part];
        acc.x = fmaf(w, v.x, acc.x);
        acc.y = fmaf(w, v.y, acc.y);
        acc.z = fmaf(w, v.z, acc.z);
        acc.w = fmaf(w, v.w, acc.w);
    }
    // self-loop
    {
        float w = di * di;
        float4 v = xk4[(size_t)node * 16 + part];
        acc.x = fmaf(w, v.x, acc.x);
        acc.y = fmaf(w, v.y, acc.y);
        acc.z = fmaf(w, v.z, acc.z);
        acc.w = fmaf(w, v.w, acc.w);
    }
    float4 v0 = ((const float4*)x0)[(size_t)node * 16 + part];
    float4 o;
    o.x = 0.9f * acc.x + ALPHA_F * v0.x;
    o.y = 0.9f * acc.y + ALPHA_F * v0.y;
    o.z = 0.9f * acc.z + ALPHA_F * v0.z;
    o.w = 0.9f * acc.w + ALPHA_F * v0.w;
    ((float4*)xn)[(size_t)node * 16 + part] = o;
}

extern "C" void kernel_launch(void* const* d_in, const int* in_sizes, int n_in,
                              void* d_out, int out_size, void* d_ws, size_t ws_size,
                              hipStream_t stream) {
    const float* x = (const float*)d_in[0];
    const void* ei = d_in[1];
    const float* w1 = (const float*)d_in[2];
    const float* b1 = (const float*)d_in[3];
    const float* w2 = (const float*)d_in[4];
    const float* b2 = (const float*)d_in[5];
    float* out = (float*)d_out;

    int n = in_sizes[0] / HIDDEN;          // 100000
    long long E = (long long)in_sizes[1] / 2;  // 3200000

    char* ws = (char*)d_ws;
    size_t off = 0;
    auto alloc = [&](size_t bytes) {
        void* p = ws + off;
        off += (bytes + 511) & ~(size_t)511;
        return p;
    };
    float* x0 = (float*)alloc((size_t)n * OUTF * 4);    // 25.6 MB (z, preserved)
    float* bufA = (float*)alloc((size_t)n * OUTF * 4);  // 25.6 MB (ping)
    int* deg = (int*)alloc((size_t)n * 4);
    float* dinv = (float*)alloc((size_t)n * 4);
    int* ofs = (int*)alloc((size_t)(n + 1) * 4);
    int* cur = (int*)alloc((size_t)n * 4);
    int* csr_src = (int*)alloc((size_t)E * 4);          // 12.8 MB

    hipMemsetAsync(deg, 0, (size_t)n * 4, stream);

    count_deg_kernel<<<(int)((E + 511) / 512), 512, 0, stream>>>(ei, E, deg, n);
    scan_kernel<<<1, 1024, 0, stream>>>(deg, ofs, n);
    dinv_kernel<<<(n + 255) / 256, 256, 0, stream>>>(deg, dinv, n);
    copy_cursor_kernel<<<(n + 255) / 256, 256, 0, stream>>>(ofs, cur, n);
    fill_csr_kernel<<<(int)((E + 511) / 512), 512, 0, stream>>>(ei, E, cur, csr_src, n);

    mlp_kernel<<<(n + MLP_BM - 1) / MLP_BM, 256, 0, stream>>>(x, w1, b1, w2, b2, x0, n);

    int prop_blocks = (int)(((size_t)n * 16 + 255) / 256);
    for (int k = 0; k < 10; ++k) {
        const float* src = (k == 0) ? x0 : ((k & 1) ? bufA : out);
        float* dst = (k & 1) ? out : bufA;
        prop_kernel<<<prop_blocks, 256, 0, stream>>>(src, x0, dst, ofs, csr_src, dinv, n);
    }
}

// Round 2
// 1648.214 us; speedup vs baseline: 1.3959x; 1.3959x over previous
//
#include <hip/hip_runtime.h>
#include <hip/hip_bf16.h>

// APPNP: z = MLP(x); then 10x: x_{k+1} = 0.9 * A_hat x_k + 0.1 * z
// A_hat = D^-1/2 (A + I) D^-1/2, degree at target (col) nodes.
// Propagation uses pre-scaled bf16 gather buffer g = dinv * x_k, so
// x_{k+1}[v] = 0.9 * dinv[v] * sum_{s in N(v) ∪ {v}} g[s] + 0.1 * x0[v].

#define HIDDEN 256
#define OUTF   64
#define ALPHA_F 0.1f

typedef __attribute__((ext_vector_type(8))) unsigned short ushort8;

__device__ inline float b2f(unsigned short u) {
    union { unsigned int i; float f; } c;
    c.i = ((unsigned int)u) << 16;
    return c.f;
}
__device__ inline unsigned short f2b(float f) {
    union { float f; unsigned int i; } c;
    c.f = f;
    unsigned int x = c.i;
    unsigned int r = (x + 0x7fff + ((x >> 16) & 1)) >> 16;  // RNE
    return (unsigned short)r;
}

// ---------- int64/int32 edge-index hedge ----------
__device__ inline bool detect_i64(const int* __restrict__ p) {
    int acc = 0;
#pragma unroll
    for (int i = 0; i < 16; ++i) acc |= p[2 * i + 1];
    return acc == 0;
}

__device__ inline int load_idx(const void* eiv, long long flat, bool is64) {
    if (is64) return (int)((const long long*)eiv)[flat];
    return ((const int*)eiv)[flat];
}

// ---------- degree count ----------
__global__ __launch_bounds__(512) void count_deg_kernel(const void* __restrict__ eiv,
                                                        long long E, int* __restrict__ deg,
                                                        int n) {
    bool is64 = detect_i64((const int*)eiv);
    long long e = (long long)blockIdx.x * blockDim.x + threadIdx.x;
    if (e >= E) return;
    int c = load_idx(eiv, E + e, is64);
    if ((unsigned)c < (unsigned)n) atomicAdd(&deg[c], 1);
}

// ---------- dinv = rsqrt(deg + 1) (self-loop included) ----------
__global__ __launch_bounds__(256) void dinv_kernel(const int* __restrict__ deg,
                                                   float* __restrict__ dinv, int n) {
    int i = blockIdx.x * 256 + threadIdx.x;
    if (i < n) dinv[i] = rsqrtf((float)(deg[i] + 1));
}

// ---------- single-block exclusive scan over deg -> ofs[0..n] ----------
__global__ __launch_bounds__(1024) void scan_kernel(const int* __restrict__ deg,
                                                    int* __restrict__ ofs, int n) {
    __shared__ int s[1024];
    __shared__ int carry_s;
    int t = threadIdx.x;
    if (t == 0) carry_s = 0;
    __syncthreads();
    for (int base = 0; base < n; base += 1024) {
        int i = base + t;
        int v = (i < n) ? deg[i] : 0;
        s[t] = v;
        __syncthreads();
        for (int o = 1; o < 1024; o <<= 1) {
            int tv = (t >= o) ? s[t - o] : 0;
            __syncthreads();
            s[t] += tv;
            __syncthreads();
        }
        int carry = carry_s;
        if (i < n) ofs[i] = carry + s[t] - v;  // exclusive
        __syncthreads();
        if (t == 0) carry_s += s[1023];
        __syncthreads();
    }
    if (t == 0) ofs[n] = carry_s;
}

__global__ __launch_bounds__(256) void copy_cursor_kernel(const int* __restrict__ ofs,
                                                          int* __restrict__ cur, int n) {
    int i = blockIdx.x * 256 + threadIdx.x;
    if (i < n) cur[i] = ofs[i];
}

// ---------- CSR fill (by target node) ----------
__global__ __launch_bounds__(512) void fill_csr_kernel(const void* __restrict__ eiv,
                                                       long long E, int* __restrict__ cur,
                                                       int* __restrict__ csr_src, int n) {
    bool is64 = detect_i64((const int*)eiv);
    long long e = (long long)blockIdx.x * blockDim.x + threadIdx.x;
    if (e >= E) return;
    int r = load_idx(eiv, e, is64);
    int c = load_idx(eiv, E + e, is64);
    if ((unsigned)c >= (unsigned)n || (unsigned)r >= (unsigned)n) return;
    int pos = atomicAdd(&cur[c], 1);
    csr_src[pos] = r;
}

// ---------- fused MLP: z = relu(x@w1.T + b1) @ w2.T + b2 ----------
// Block: 256 threads, 64 nodes. fp32, LDS-staged tiles.
// LDS: union({xs,w1s}, w2s) + hs = 34.3 KB -> 4 blocks/CU.
#define MLP_BM 64
__global__ __launch_bounds__(256) void mlp_kernel(const float* __restrict__ x,
                                                  const float* __restrict__ w1,
                                                  const float* __restrict__ b1,
                                                  const float* __restrict__ w2,
                                                  const float* __restrict__ b2,
                                                  float* __restrict__ z, int n) {
    __shared__ union {
        struct {
            float xs[MLP_BM][33];   // [m][k2]
            float w1s[32][73];      // [k2][f_local]; stride 73 -> (9k+f)%32 conflict-free writes
        } p1;
        float w2s[64][72];          // [j][f_local]
    } u;
    __shared__ float hs[MLP_BM][65];  // [m][f_local]

    int t = threadIdx.x;
    int mg = t & 31;        // node sub-index (m and m+32)
    int fg = t >> 5;        // feature group 0..7
    int node0 = blockIdx.x * MLP_BM;

    float zacc[2][8];
#pragma unroll
    for (int a = 0; a < 2; ++a)
#pragma unroll
        for (int b = 0; b < 8; ++b) zacc[a][b] = 0.f;

    for (int fb = 0; fb < 4; ++fb) {
        int f0 = fb * 64;
        float hacc[2][8];
#pragma unroll
        for (int a = 0; a < 2; ++a)
#pragma unroll
            for (int b = 0; b < 8; ++b) hacc[a][b] = 0.f;

        for (int kb = 0; kb < 8; ++kb) {
            int k0 = kb * 32;
            // stage xs: 64 nodes x 32 k
#pragma unroll
            for (int i = 0; i < 8; ++i) {
                int q = i * 256 + t;
                int m = q >> 5, k = q & 31;
                int node = node0 + m;
                u.p1.xs[m][k] = (node < n) ? x[(size_t)node * HIDDEN + k0 + k] : 0.f;
            }
            // stage w1s transposed: 64 f x 32 k
#pragma unroll
            for (int i = 0; i < 8; ++i) {
                int q = i * 256 + t;
                int f = q >> 5, k = q & 31;
                u.p1.w1s[k][f] = w1[(size_t)(f0 + f) * HIDDEN + k0 + k];
            }
            __syncthreads();
#pragma unroll 8
            for (int k2 = 0; k2 < 32; ++k2) {
                float xa = u.p1.xs[mg][k2];
                float xb = u.p1.xs[mg + 32][k2];
                const float4 wlo = *(const float4*)&u.p1.w1s[k2][fg * 8];
                const float4 whi = *(const float4*)&u.p1.w1s[k2][fg * 8 + 4];
                hacc[0][0] = fmaf(xa, wlo.x, hacc[0][0]);
                hacc[0][1] = fmaf(xa, wlo.y, hacc[0][1]);
                hacc[0][2] = fmaf(xa, wlo.z, hacc[0][2]);
                hacc[0][3] = fmaf(xa, wlo.w, hacc[0][3]);
                hacc[0][4] = fmaf(xa, whi.x, hacc[0][4]);
                hacc[0][5] = fmaf(xa, whi.y, hacc[0][5]);
                hacc[0][6] = fmaf(xa, whi.z, hacc[0][6]);
                hacc[0][7] = fmaf(xa, whi.w, hacc[0][7]);
                hacc[1][0] = fmaf(xb, wlo.x, hacc[1][0]);
                hacc[1][1] = fmaf(xb, wlo.y, hacc[1][1]);
                hacc[1][2] = fmaf(xb, wlo.z, hacc[1][2]);
                hacc[1][3] = fmaf(xb, wlo.w, hacc[1][3]);
                hacc[1][4] = fmaf(xb, whi.x, hacc[1][4]);
                hacc[1][5] = fmaf(xb, whi.y, hacc[1][5]);
                hacc[1][6] = fmaf(xb, whi.z, hacc[1][6]);
                hacc[1][7] = fmaf(xb, whi.w, hacc[1][7]);
            }
            __syncthreads();
        }
        // bias + relu -> hs
#pragma unroll
        for (int ff = 0; ff < 8; ++ff) {
            int f = fg * 8 + ff;
            float bb = b1[f0 + f];
            hs[mg][f] = fmaxf(hacc[0][ff] + bb, 0.f);
            hs[mg + 32][f] = fmaxf(hacc[1][ff] + bb, 0.f);
        }
        __syncthreads();  // hs ready AND p1 dead before w2s overwrite
        // stage w2s: 64 j x 64 f (float4)
#pragma unroll
        for (int i = 0; i < 4; ++i) {
            int q = i * 256 + t;  // 1024 float4 slots
            int j = q >> 4, f4 = q & 15;
            *(float4*)&u.w2s[j][f4 * 4] = *(const float4*)&w2[(size_t)j * HIDDEN + f0 + f4 * 4];
        }
        __syncthreads();
        // z-phase
#pragma unroll 4
        for (int f2 = 0; f2 < 64; ++f2) {
            float ha = hs[mg][f2];
            float hb = hs[mg + 32][f2];
#pragma unroll
            for (int jj = 0; jj < 8; ++jj) {
                float wv = u.w2s[fg * 8 + jj][f2];
                zacc[0][jj] = fmaf(ha, wv, zacc[0][jj]);
                zacc[1][jj] = fmaf(hb, wv, zacc[1][jj]);
            }
        }
        __syncthreads();
    }
    // transpose z through hs for coalesced store
#pragma unroll
    for (int jj = 0; jj < 8; ++jj) {
        hs[mg][fg * 8 + jj] = zacc[0][jj];
        hs[mg + 32][fg * 8 + jj] = zacc[1][jj];
    }
    __syncthreads();
#pragma unroll
    for (int i = 0; i < 16; ++i) {
        int q = i * 256 + t;
        int m = q >> 6, j = q & 63;
        int node = node0 + m;
        if (node < n) z[(size_t)node * OUTF + j] = hs[m][j] + b2[j];
    }
}

// ---------- init: g0 = bf16(dinv * x0) ----------
__global__ __launch_bounds__(256) void init_g_kernel(const float* __restrict__ x0,
                                                     const float* __restrict__ dinv,
                                                     unsigned short* __restrict__ g, int n) {
    int gid = blockIdx.x * 256 + threadIdx.x;
    int node = gid >> 3;
    int part = gid & 7;
    if (node >= n) return;
    float di = dinv[node];
    const float4* x4 = (const float4*)(x0 + (size_t)node * OUTF + part * 8);
    float4 a = x4[0], b = x4[1];
    ushort8 o;
    o[0] = f2b(di * a.x); o[1] = f2b(di * a.y); o[2] = f2b(di * a.z); o[3] = f2b(di * a.w);
    o[4] = f2b(di * b.x); o[5] = f2b(di * b.y); o[6] = f2b(di * b.z); o[7] = f2b(di * b.w);
    *(ushort8*)(g + (size_t)node * OUTF + part * 8) = o;
}

// ---------- propagation step ----------
// 8 threads per node, 8 bf16 feats (16B) per thread.
// acc = sum of g over neighbors+self; out = 0.9*di*acc + 0.1*x0.
// Writes g_next = bf16(di * out) unless LAST, then writes fp32 out.
template <int LAST>
__global__ __launch_bounds__(256) void prop_kernel(const unsigned short* __restrict__ gk,
                                                   const float* __restrict__ x0,
                                                   unsigned short* __restrict__ gn,
                                                   float* __restrict__ out,
                                                   const int* __restrict__ ofs,
                                                   const int* __restrict__ csr_src,
                                                   const float* __restrict__ dinv, int n) {
    int gid = blockIdx.x * 256 + threadIdx.x;
    int node = gid >> 3;
    int part = gid & 7;
    if (node >= n) return;

    int beg = ofs[node];
    int end = ofs[node + 1];
    float di = dinv[node];

    float acc[8];
#pragma unroll
    for (int j = 0; j < 8; ++j) acc[j] = 0.f;

    const size_t poff = (size_t)part * 8;
    int e = beg;
    for (; e + 1 < end; e += 2) {
        int s0 = csr_src[e];
        int s1 = csr_src[e + 1];
        ushort8 a = *(const ushort8*)(gk + (size_t)s0 * OUTF + poff);
        ushort8 b = *(const ushort8*)(gk + (size_t)s1 * OUTF + poff);
#pragma unroll
        for (int j = 0; j < 8; ++j) acc[j] += b2f(a[j]);
#pragma unroll
        for (int j = 0; j < 8; ++j) acc[j] += b2f(b[j]);
    }
    if (e < end) {
        int s0 = csr_src[e];
        ushort8 a = *(const ushort8*)(gk + (size_t)s0 * OUTF + poff);
#pragma unroll
        for (int j = 0; j < 8; ++j) acc[j] += b2f(a[j]);
    }
    // self-loop
    {
        ushort8 a = *(const ushort8*)(gk + (size_t)node * OUTF + poff);
#pragma unroll
        for (int j = 0; j < 8; ++j) acc[j] += b2f(a[j]);
    }

    const float4* x4 = (const float4*)(x0 + (size_t)node * OUTF + poff);
    float4 v0a = x4[0], v0b = x4[1];
    float res[8];
    res[0] = 0.9f * di * acc[0] + ALPHA_F * v0a.x;
    res[1] = 0.9f * di * acc[1] + ALPHA_F * v0a.y;
    res[2] = 0.9f * di * acc[2] + ALPHA_F * v0a.z;
    res[3] = 0.9f * di * acc[3] + ALPHA_F * v0a.w;
    res[4] = 0.9f * di * acc[4] + ALPHA_F * v0b.x;
    res[5] = 0.9f * di * acc[5] + ALPHA_F * v0b.y;
    res[6] = 0.9f * di * acc[6] + ALPHA_F * v0b.z;
    res[7] = 0.9f * di * acc[7] + ALPHA_F * v0b.w;

    if (LAST) {
        float4* o4 = (float4*)(out + (size_t)node * OUTF + poff);
        o4[0] = make_float4(res[0], res[1], res[2], res[3]);
        o4[1] = make_float4(res[4], res[5], res[6], res[7]);
    } else {
        ushort8 o;
#pragma unroll
        for (int j = 0; j < 8; ++j) o[j] = f2b(di * res[j]);
        *(ushort8*)(gn + (size_t)node * OUTF + poff) = o;
    }
}

extern "C" void kernel_launch(void* const* d_in, const int* in_sizes, int n_in,
                              void* d_out, int out_size, void* d_ws, size_t ws_size,
                              hipStream_t stream) {
    const float* x = (const float*)d_in[0];
    const void* ei = d_in[1];
    const float* w1 = (const float*)d_in[2];
    const float* b1 = (const float*)d_in[3];
    const float* w2 = (const float*)d_in[4];
    const float* b2 = (const float*)d_in[5];
    float* out = (float*)d_out;

    int n = in_sizes[0] / HIDDEN;              // 100000
    long long E = (long long)in_sizes[1] / 2;  // 3200000

    char* ws = (char*)d_ws;
    size_t off = 0;
    auto alloc = [&](size_t bytes) {
        void* p = ws + off;
        off += (bytes + 511) & ~(size_t)511;
        return p;
    };
    float* x0 = (float*)alloc((size_t)n * OUTF * 4);              // 25.6 MB (z)
    unsigned short* gA = (unsigned short*)alloc((size_t)n * OUTF * 2);  // 12.8 MB
    unsigned short* gB = (unsigned short*)alloc((size_t)n * OUTF * 2);  // 12.8 MB
    int* deg = (int*)alloc((size_t)n * 4);
    float* dinv = (float*)alloc((size_t)n * 4);
    int* ofs = (int*)alloc((size_t)(n + 1) * 4);
    int* cur = (int*)alloc((size_t)n * 4);
    int* csr_src = (int*)alloc((size_t)E * 4);                    // 12.8 MB

    hipMemsetAsync(deg, 0, (size_t)n * 4, stream);

    count_deg_kernel<<<(int)((E + 511) / 512), 512, 0, stream>>>(ei, E, deg, n);
    scan_kernel<<<1, 1024, 0, stream>>>(deg, ofs, n);
    dinv_kernel<<<(n + 255) / 256, 256, 0, stream>>>(deg, dinv, n);
    copy_cursor_kernel<<<(n + 255) / 256, 256, 0, stream>>>(ofs, cur, n);
    fill_csr_kernel<<<(int)((E + 511) / 512), 512, 0, stream>>>(ei, E, cur, csr_src, n);

    mlp_kernel<<<(n + MLP_BM - 1) / MLP_BM, 256, 0, stream>>>(x, w1, b1, w2, b2, x0, n);

    int prop_blocks = (int)(((size_t)n * 8 + 255) / 256);
    init_g_kernel<<<prop_blocks, 256, 0, stream>>>(x0, dinv, gA, n);

    for (int k = 0; k < 10; ++k) {
        const unsigned short* gin = (k & 1) ? gB : gA;
        unsigned short* gout = (k & 1) ? gA : gB;
        if (k == 9) {
            prop_kernel<1><<<prop_blocks, 256, 0, stream>>>(gin, x0, nullptr, out, ofs,
                                                            csr_src, dinv, n);
        } else {
            prop_kernel<0><<<prop_blocks, 256, 0, stream>>>(gin, x0, gout, nullptr, ofs,
                                                            csr_src, dinv, n);
        }
    }
}

// Round 3
// 1077.924 us; speedup vs baseline: 2.1344x; 1.5291x over previous
//
#include <hip/hip_runtime.h>
#include <hip/hip_bf16.h>

// APPNP: z = MLP(x); then 10x: x_{k+1} = 0.9 * A_hat x_k + 0.1 * z
// MLP runs as bf16 MFMA (16x16x32); propagation gathers pre-scaled bf16 rows.

#define HIDDEN 256
#define OUTF   64
#define ALPHA_F 0.1f

typedef __attribute__((ext_vector_type(8))) unsigned short ushort8;
typedef __attribute__((ext_vector_type(8))) short short8v;   // 8 bf16 MFMA frag
typedef __attribute__((ext_vector_type(4))) float f32x4;     // MFMA acc

__device__ inline float b2f(unsigned short u) {
    union { unsigned int i; float f; } c;
    c.i = ((unsigned int)u) << 16;
    return c.f;
}
__device__ inline unsigned short f2b(float f) {
    union { float f; unsigned int i; } c;
    c.f = f;
    unsigned int x = c.i;
    unsigned int r = (x + 0x7fff + ((x >> 16) & 1)) >> 16;  // RNE
    return (unsigned short)r;
}

// ---------- int64/int32 edge-index hedge ----------
__device__ inline bool detect_i64(const int* __restrict__ p) {
    int acc = 0;
#pragma unroll
    for (int i = 0; i < 16; ++i) acc |= p[2 * i + 1];
    return acc == 0;
}

__device__ inline int load_idx(const void* eiv, long long flat, bool is64) {
    if (is64) return (int)((const long long*)eiv)[flat];
    return ((const int*)eiv)[flat];
}

// ---------- degree count ----------
__global__ __launch_bounds__(512) void count_deg_kernel(const void* __restrict__ eiv,
                                                        long long E, int* __restrict__ deg,
                                                        int n) {
    bool is64 = detect_i64((const int*)eiv);
    long long e = (long long)blockIdx.x * blockDim.x + threadIdx.x;
    if (e >= E) return;
    int c = load_idx(eiv, E + e, is64);
    if ((unsigned)c < (unsigned)n) atomicAdd(&deg[c], 1);
}

// ---------- dinv = rsqrt(deg + 1) ----------
__global__ __launch_bounds__(256) void dinv_kernel(const int* __restrict__ deg,
                                                   float* __restrict__ dinv, int n) {
    int i = blockIdx.x * 256 + threadIdx.x;
    if (i < n) dinv[i] = rsqrtf((float)(deg[i] + 1));
}

// ---------- multi-block exclusive scan: deg -> ofs[0..n] ----------
__global__ __launch_bounds__(1024) void scan1_kernel(const int* __restrict__ deg,
                                                     int* __restrict__ ofs,
                                                     int* __restrict__ bsum, int n) {
    __shared__ int s[1024];
    int t = threadIdx.x;
    int i = blockIdx.x * 1024 + t;
    int v = (i < n) ? deg[i] : 0;
    s[t] = v;
    __syncthreads();
    for (int o = 1; o < 1024; o <<= 1) {
        int tv = (t >= o) ? s[t - o] : 0;
        __syncthreads();
        s[t] += tv;
        __syncthreads();
    }
    if (i < n) ofs[i] = s[t] - v;  // block-local exclusive
    if (t == 1023) bsum[blockIdx.x] = s[1023];
}

__global__ __launch_bounds__(1024) void scan2_kernel(const int* __restrict__ bsum,
                                                     int* __restrict__ bofs, int nb) {
    __shared__ int s[1024];
    int t = threadIdx.x;
    int v = (t < nb) ? bsum[t] : 0;
    s[t] = v;
    __syncthreads();
    for (int o = 1; o < 1024; o <<= 1) {
        int tv = (t >= o) ? s[t - o] : 0;
        __syncthreads();
        s[t] += tv;
        __syncthreads();
    }
    if (t < nb) bofs[t] = s[t] - v;
    if (t == 1023) bofs[nb] = s[1023];  // grand total
}

__global__ __launch_bounds__(1024) void scan3_kernel(int* __restrict__ ofs,
                                                     const int* __restrict__ bofs,
                                                     int n, int nb) {
    int i = blockIdx.x * 1024 + threadIdx.x;
    if (i < n) ofs[i] += bofs[blockIdx.x];
    if (i == 0) ofs[n] = bofs[nb];
}

__global__ __launch_bounds__(256) void copy_cursor_kernel(const int* __restrict__ ofs,
                                                          int* __restrict__ cur, int n) {
    int i = blockIdx.x * 256 + threadIdx.x;
    if (i < n) cur[i] = ofs[i];
}

// ---------- CSR fill (by target node) ----------
__global__ __launch_bounds__(512) void fill_csr_kernel(const void* __restrict__ eiv,
                                                       long long E, int* __restrict__ cur,
                                                       int* __restrict__ csr_src, int n) {
    bool is64 = detect_i64((const int*)eiv);
    long long e = (long long)blockIdx.x * blockDim.x + threadIdx.x;
    if (e >= E) return;
    int r = load_idx(eiv, e, is64);
    int c = load_idx(eiv, E + e, is64);
    if ((unsigned)c >= (unsigned)n || (unsigned)r >= (unsigned)n) return;
    int pos = atomicAdd(&cur[c], 1);
    csr_src[pos] = r;
}

// ---------- fused MFMA MLP: z = relu(x@w1.T + b1) @ w2.T + b2 ----------
// 256 threads = 4 waves, 64 nodes/block. bf16 MFMA 16x16x32.
// Fragment pattern (m90-m97 verified): A lane l holds row l&15, k=(l>>4)*8..+7;
// B (row-major [out,K]) identical pattern; C/D: col=lane&15, row=(lane>>4)*4+r.
// LDS staged in fragment-linear unit order so wave frag reads are lane-linear.
#define MLP_BM 64
__global__ __launch_bounds__(256) void mlp_mfma_kernel(const float* __restrict__ x,
                                                       const float* __restrict__ w1,
                                                       const float* __restrict__ b1,
                                                       const float* __restrict__ w2,
                                                       const float* __restrict__ b2,
                                                       float* __restrict__ z, int n) {
    // regA: phase1 = w1 chunk (1024 units) + x chunk (256 units); phase2 = w2 (2048 units)
    __shared__ __align__(16) unsigned short regA[16384];      // 32 KB
    __shared__ __align__(16) unsigned short h_lds[64 * 264];  // 33 KB, stride 264 bf16 (528B, 16B-mult)

    const int t = threadIdx.x;
    const int w = t >> 6;       // wave 0..3
    const int l = t & 63;       // lane
    const int c = l & 15, g = l >> 4;
    const int node0 = blockIdx.x * MLP_BM;

    f32x4 acc[4][4];  // [mtile][ntile] ; wave owns N-cols [w*64, w*64+64)
#pragma unroll
    for (int a = 0; a < 4; ++a)
#pragma unroll
        for (int b = 0; b < 4; ++b) acc[a][b] = (f32x4)0.f;

    // ---- phase 1: h = relu(x @ w1.T + b1), K loop over 8 chunks of 32 ----
    for (int ks = 0; ks < 8; ++ks) {
        const int k0 = ks * 32;
        // stage x chunk: unit(m,kg) -> idx 8192 + ((m>>4)*64 + kg*16 + (m&15))*8
        {
            int kg = t & 3, m = t >> 2;
            int node = node0 + m;
            float4 A = make_float4(0.f, 0.f, 0.f, 0.f), B = A;
            if (node < n) {
                const float4* xp = (const float4*)(x + (size_t)node * HIDDEN + k0 + kg * 8);
                A = xp[0];
                B = xp[1];
            }
            short8v o;
            o[0] = (short)f2b(A.x); o[1] = (short)f2b(A.y);
            o[2] = (short)f2b(A.z); o[3] = (short)f2b(A.w);
            o[4] = (short)f2b(B.x); o[5] = (short)f2b(B.y);
            o[6] = (short)f2b(B.z); o[7] = (short)f2b(B.w);
            *(short8v*)&regA[8192 + (((m >> 4) * 64 + kg * 16 + (m & 15)) << 3)] = o;
        }
        // stage w1 chunk: 4 passes, unit(f,kg) -> idx ((f>>4)*64 + kg*16 + (f&15))*8
#pragma unroll
        for (int p = 0; p < 4; ++p) {
            int kg = t & 3, f = p * 64 + (t >> 2);
            const float4* wp = (const float4*)(w1 + (size_t)f * HIDDEN + k0 + kg * 8);
            float4 A = wp[0], B = wp[1];
            short8v o;
            o[0] = (short)f2b(A.x); o[1] = (short)f2b(A.y);
            o[2] = (short)f2b(A.z); o[3] = (short)f2b(A.w);
            o[4] = (short)f2b(B.x); o[5] = (short)f2b(B.y);
            o[6] = (short)f2b(B.z); o[7] = (short)f2b(B.w);
            *(short8v*)&regA[(((f >> 4) * 64 + kg * 16 + (f & 15)) << 3)] = o;
        }
        __syncthreads();
        short8v af[4], bf[4];
#pragma unroll
        for (int mt = 0; mt < 4; ++mt)
            af[mt] = *(const short8v*)&regA[8192 + ((mt * 64 + l) << 3)];
#pragma unroll
        for (int nt = 0; nt < 4; ++nt)
            bf[nt] = *(const short8v*)&regA[(((w * 4 + nt) * 64 + l) << 3)];
#pragma unroll
        for (int mt = 0; mt < 4; ++mt)
#pragma unroll
            for (int nt = 0; nt < 4; ++nt)
                acc[mt][nt] =
                    __builtin_amdgcn_mfma_f32_16x16x32_bf16(af[mt], bf[nt], acc[mt][nt], 0, 0, 0);
        __syncthreads();
    }

    // ---- bias + relu -> h_lds (bf16), and stage w2 into regA ----
#pragma unroll
    for (int nt = 0; nt < 4; ++nt) {
        int col = w * 64 + nt * 16 + c;
        float b1v = b1[col];
#pragma unroll
        for (int mt = 0; mt < 4; ++mt)
#pragma unroll
            for (int r = 0; r < 4; ++r) {
                int row = mt * 16 + g * 4 + r;
                float hv = fmaxf(acc[mt][nt][r] + b1v, 0.f);
                h_lds[row * 264 + col] = f2b(hv);
            }
    }
    // stage w2 (64x256): unit(j,kslot) -> idx ((j>>4)*512 + (kslot>>2)*64 + (kslot&3)*16 + (j&15))*8
#pragma unroll
    for (int p = 0; p < 8; ++p) {
        int j = p * 8 + (t >> 5);
        int kslot = t & 31;
        const float4* wp = (const float4*)(w2 + (size_t)j * HIDDEN + kslot * 8);
        float4 A = wp[0], B = wp[1];
        short8v o;
        o[0] = (short)f2b(A.x); o[1] = (short)f2b(A.y);
        o[2] = (short)f2b(A.z); o[3] = (short)f2b(A.w);
        o[4] = (short)f2b(B.x); o[5] = (short)f2b(B.y);
        o[6] = (short)f2b(B.z); o[7] = (short)f2b(B.w);
        *(short8v*)&regA[(((j >> 4) * 512 + (kslot >> 2) * 64 + (kslot & 3) * 16 + (j & 15)) << 3)] = o;
    }
    __syncthreads();

    // ---- phase 2: z = h @ w2.T + b2 ; wave w owns rows [w*16, w*16+16) ----
    f32x4 acc2[4];
#pragma unroll
    for (int nt = 0; nt < 4; ++nt) acc2[nt] = (f32x4)0.f;
#pragma unroll
    for (int ks = 0; ks < 8; ++ks) {
        short8v a2 = *(const short8v*)&h_lds[(w * 16 + c) * 264 + ks * 32 + g * 8];
#pragma unroll
        for (int nt = 0; nt < 4; ++nt) {
            short8v b2v = *(const short8v*)&regA[((nt * 512 + ks * 64 + l) << 3)];
            acc2[nt] = __builtin_amdgcn_mfma_f32_16x16x32_bf16(a2, b2v, acc2[nt], 0, 0, 0);
        }
    }
#pragma unroll
    for (int nt = 0; nt < 4; ++nt) {
        int col = nt * 16 + c;
        float bb = b2[col];
#pragma unroll
        for (int r = 0; r < 4; ++r) {
            int node = node0 + w * 16 + g * 4 + r;
            if (node < n) z[(size_t)node * OUTF + col] = acc2[nt][r] + bb;
        }
    }
}

// ---------- init: g0 = bf16(dinv * x0) ----------
__global__ __launch_bounds__(256) void init_g_kernel(const float* __restrict__ x0,
                                                     const float* __restrict__ dinv,
                                                     unsigned short* __restrict__ g, int n) {
    int gid = blockIdx.x * 256 + threadIdx.x;
    int node = gid >> 3;
    int part = gid & 7;
    if (node >= n) return;
    float di = dinv[node];
    const float4* x4 = (const float4*)(x0 + (size_t)node * OUTF + part * 8);
    float4 a = x4[0], b = x4[1];
    ushort8 o;
    o[0] = f2b(di * a.x); o[1] = f2b(di * a.y); o[2] = f2b(di * a.z); o[3] = f2b(di * a.w);
    o[4] = f2b(di * b.x); o[5] = f2b(di * b.y); o[6] = f2b(di * b.z); o[7] = f2b(di * b.w);
    *(ushort8*)(g + (size_t)node * OUTF + part * 8) = o;
}

// ---------- propagation step ----------
template <int LAST>
__global__ __launch_bounds__(256) void prop_kernel(const unsigned short* __restrict__ gk,
                                                   const float* __restrict__ x0,
                                                   unsigned short* __restrict__ gn,
                                                   float* __restrict__ out,
                                                   const int* __restrict__ ofs,
                                                   const int* __restrict__ csr_src,
                                                   const float* __restrict__ dinv, int n) {
    int gid = blockIdx.x * 256 + threadIdx.x;
    int node = gid >> 3;
    int part = gid & 7;
    if (node >= n) return;

    int beg = ofs[node];
    int end = ofs[node + 1];
    float di = dinv[node];

    float acc[8];
#pragma unroll
    for (int j = 0; j < 8; ++j) acc[j] = 0.f;

    const size_t poff = (size_t)part * 8;
    int e = beg;
    for (; e + 1 < end; e += 2) {
        int s0 = csr_src[e];
        int s1 = csr_src[e + 1];
        ushort8 a = *(const ushort8*)(gk + (size_t)s0 * OUTF + poff);
        ushort8 b = *(const ushort8*)(gk + (size_t)s1 * OUTF + poff);
#pragma unroll
        for (int j = 0; j < 8; ++j) acc[j] += b2f(a[j]);
#pragma unroll
        for (int j = 0; j < 8; ++j) acc[j] += b2f(b[j]);
    }
    if (e < end) {
        int s0 = csr_src[e];
        ushort8 a = *(const ushort8*)(gk + (size_t)s0 * OUTF + poff);
#pragma unroll
        for (int j = 0; j < 8; ++j) acc[j] += b2f(a[j]);
    }
    {
        ushort8 a = *(const ushort8*)(gk + (size_t)node * OUTF + poff);
#pragma unroll
        for (int j = 0; j < 8; ++j) acc[j] += b2f(a[j]);
    }

    const float4* x4 = (const float4*)(x0 + (size_t)node * OUTF + poff);
    float4 v0a = x4[0], v0b = x4[1];
    float res[8];
    res[0] = 0.9f * di * acc[0] + ALPHA_F * v0a.x;
    res[1] = 0.9f * di * acc[1] + ALPHA_F * v0a.y;
    res[2] = 0.9f * di * acc[2] + ALPHA_F * v0a.z;
    res[3] = 0.9f * di * acc[3] + ALPHA_F * v0a.w;
    res[4] = 0.9f * di * acc[4] + ALPHA_F * v0b.x;
    res[5] = 0.9f * di * acc[5] + ALPHA_F * v0b.y;
    res[6] = 0.9f * di * acc[6] + ALPHA_F * v0b.z;
    res[7] = 0.9f * di * acc[7] + ALPHA_F * v0b.w;

    if (LAST) {
        float4* o4 = (float4*)(out + (size_t)node * OUTF + poff);
        o4[0] = make_float4(res[0], res[1], res[2], res[3]);
        o4[1] = make_float4(res[4], res[5], res[6], res[7]);
    } else {
        ushort8 o;
#pragma unroll
        for (int j = 0; j < 8; ++j) o[j] = f2b(di * res[j]);
        *(ushort8*)(gn + (size_t)node * OUTF + poff) = o;
    }
}

extern "C" void kernel_launch(void* const* d_in, const int* in_sizes, int n_in,
                              void* d_out, int out_size, void* d_ws, size_t ws_size,
                              hipStream_t stream) {
    const float* x = (const float*)d_in[0];
    const void* ei = d_in[1];
    const float* w1 = (const float*)d_in[2];
    const float* b1 = (const float*)d_in[3];
    const float* w2 = (const float*)d_in[4];
    const float* b2 = (const float*)d_in[5];
    float* out = (float*)d_out;

    int n = in_sizes[0] / HIDDEN;              // 100000
    long long E = (long long)in_sizes[1] / 2;  // 3200000
    int nb = (n + 1023) / 1024;

    char* ws = (char*)d_ws;
    size_t off = 0;
    auto alloc = [&](size_t bytes) {
        void* p = ws + off;
        off += (bytes + 511) & ~(size_t)511;
        return p;
    };
    float* x0 = (float*)alloc((size_t)n * OUTF * 4);                    // z
    unsigned short* gA = (unsigned short*)alloc((size_t)n * OUTF * 2);
    unsigned short* gB = (unsigned short*)alloc((size_t)n * OUTF * 2);
    int* deg = (int*)alloc((size_t)n * 4);
    float* dinv = (float*)alloc((size_t)n * 4);
    int* ofs = (int*)alloc((size_t)(n + 1) * 4);
    int* cur = (int*)alloc((size_t)n * 4);
    int* bsum = (int*)alloc((size_t)nb * 4);
    int* bofs = (int*)alloc((size_t)(nb + 1) * 4);
    int* csr_src = (int*)alloc((size_t)E * 4);

    hipMemsetAsync(deg, 0, (size_t)n * 4, stream);

    count_deg_kernel<<<(int)((E + 511) / 512), 512, 0, stream>>>(ei, E, deg, n);
    scan1_kernel<<<nb, 1024, 0, stream>>>(deg, ofs, bsum, n);
    scan2_kernel<<<1, 1024, 0, stream>>>(bsum, bofs, nb);
    scan3_kernel<<<nb, 1024, 0, stream>>>(ofs, bofs, n, nb);
    dinv_kernel<<<(n + 255) / 256, 256, 0, stream>>>(deg, dinv, n);
    copy_cursor_kernel<<<(n + 255) / 256, 256, 0, stream>>>(ofs, cur, n);
    fill_csr_kernel<<<(int)((E + 511) / 512), 512, 0, stream>>>(ei, E, cur, csr_src, n);

    mlp_mfma_kernel<<<(n + MLP_BM - 1) / MLP_BM, 256, 0, stream>>>(x, w1, b1, w2, b2, x0, n);

    int prop_blocks = (int)(((size_t)n * 8 + 255) / 256);
    init_g_kernel<<<prop_blocks, 256, 0, stream>>>(x0, dinv, gA, n);

    for (int k = 0; k < 10; ++k) {
        const unsigned short* gin = (k & 1) ? gB : gA;
        unsigned short* gout = (k & 1) ? gA : gB;
        if (k == 9) {
            prop_kernel<1><<<prop_blocks, 256, 0, stream>>>(gin, x0, nullptr, out, ofs,
                                                            csr_src, dinv, n);
        } else {
            prop_kernel<0><<<prop_blocks, 256, 0, stream>>>(gin, x0, gout, nullptr, ofs,
                                                            csr_src, dinv, n);
        }
    }
}